// Round 7
// baseline (24077.055 us; speedup 1.0000x reference)
//
#include <hip/hip_runtime.h>
#include <cstdint>
#include <cstddef>

// ---------------------------------------------------------------------------
// StepWiseMLPAutoEncoder (MI355X/gfx950) — round 11: batch-sliced compute +
// PROVEN global barrier.
//   r10 failed (absmax 0.228, run-variant -> race): independent group drift
//   broke the r7 visibility protocol ("first cached read of a mutable line
//   happens after its last write, dispatch-wide") via cross-group line/sector
//   sharing. The per-output arithmetic was verified bit-identical to r7.
//   r11 keeps r10's compute structure (8 row-groups x 32 wgs; per-wg act
//   read 271KB -> 34KB staged once into LDS; col-partitioned L2-hot weights)
//   but reverts to r7's GLOBAL zero-RMW flag barrier, restoring the exact
//   ordering guarantee that passed in r7/r8. Stage split into issue-then-
//   write (one latency exposure, 5 float4 regs, no VGPR cliff).
// ---------------------------------------------------------------------------

#define TT 256
#define BB 64
#define SS 1024

#define EK1 2049
#define EN1 944
#define EN2 416
#define EN3 32

#define DN1 1046
#define DN2 1035
#define DN3 1024

// K paddings (quad-multiples) and padded WT row counts
#define KP1 1060   // 32 ctrl + 1024 prev + 1 t + 3 pad
#define KP2 1048   // 1046 + 2
#define KP3 1036   // 1035 + 1
#define NQ1 265
#define NQ2 262
#define NQ3 259
#define WROWS1 1048
#define WROWS2 1040
#define WROWS3 1028

// ws layout (float offsets)
#define OFF_XT    ((size_t)0)                        // xt: dead after E1
#define OFF_WT1   ((size_t)0)                        //  1048*1060 = 1,110,880
#define OFF_WT2   ((size_t)1110880)                  //  1040*1048 = 1,089,920
#define OFF_WT3   ((size_t)2200800)                  //  1028*1036 -> ends 3,265,808
#define OFF_H1S   ((size_t)3266048)                  // 256 x 67,072 -> ends 20,436,480
#define OFF_H2S   ((size_t)20436480)                 // 256 x 66,304 -> ends 37,410,304
#define OFF_E1    ((size_t)16777216)                 // encoder-time only
#define OFF_E2    ((size_t)(OFF_E1 + 15466496))      // encoder-time only
#define OFF_COMB  ((size_t)(OFF_E2 + 6815744))       // 39,059,456: 257*265*256
#define OFF_BAR   ((size_t)(OFF_COMB + 17434880))    // 256 flag words (+pad)
// total ~226 MB

#define COMB_SLOT (265 * 256)
#define H1_SLOT   (262 * 256)
#define H2_SLOT   (259 * 256)

typedef unsigned uint4v __attribute__((ext_vector_type(4)));

// ---------------------------------------------------------------------------
__global__ void zero_init(float* __restrict__ p, size_t n) {
  size_t i = (size_t)blockIdx.x * blockDim.x + threadIdx.x;
  size_t stride = (size_t)gridDim.x * blockDim.x;
  for (; i < n; i += stride) p[i] = 0.f;
}

// x[b][s][t] -> xt[b][t][s]
__global__ void transpose_x(const float* __restrict__ x, float* __restrict__ xt) {
  __shared__ float tile[32][33];
  int b = blockIdx.z;
  int s0 = blockIdx.x << 5;
  int t0 = blockIdx.y << 5;
  int lt = threadIdx.x & 31;
  int ls = threadIdx.x >> 5;
  const float* xp = x + (size_t)b * SS * TT;
#pragma unroll
  for (int i = 0; i < 4; i++) {
    int s = s0 + ls + (i << 3);
    tile[ls + (i << 3)][lt] = xp[(size_t)s * TT + t0 + lt];
  }
  __syncthreads();
  float* xtp = xt + (size_t)b * TT * SS;
#pragma unroll
  for (int i = 0; i < 4; i++) {
    int t = t0 + ls + (i << 3);
    xtp[(size_t)t * SS + s0 + lt] = tile[lt][ls + (i << 3)];
  }
}

// W[k][n] -> WT[c][k], zero-padded to KPAD cols / NCP rows
__global__ void transpose_w(const float* __restrict__ W, float* __restrict__ WT,
                            int K, int N, int KPAD, int NCP) {
  __shared__ float tl[32][33];
  int c0 = blockIdx.x << 5, k0 = blockIdx.y << 5;
  int lx = threadIdx.x & 31, ly = threadIdx.x >> 5;  // 0..7
#pragma unroll
  for (int i = 0; i < 4; i++) {
    int k = k0 + ly + (i << 3);
    int c = c0 + lx;
    tl[ly + (i << 3)][lx] = (k < K && c < N) ? W[(size_t)k * N + c] : 0.f;
  }
  __syncthreads();
#pragma unroll
  for (int i = 0; i < 4; i++) {
    int c = c0 + ly + (i << 3);
    int k = k0 + lx;
    if (c < NCP && k < KPAD) WT[(size_t)c * KPAD + k] = tl[lx][ly + (i << 3)];
  }
}

// comb[t][quad 264][r][0] = t/256, [1..3] = 0
__global__ void init_tail(float* __restrict__ comb) {
  int i = blockIdx.x * blockDim.x + threadIdx.x;  // 0..16383
  int t = i >> 6, r = i & 63;
  float4 v;
  v.x = (float)t * (1.f / 256.f);
  v.y = v.z = v.w = 0.f;
  *(float4*)(comb + ((size_t)t * 265 + 264) * 256 + (r << 2)) = v;
}

// virtual A for encoder layer 1: row m=(b,t), k: [prev(1024) | cur(1024) | t | pad]
__device__ inline float4 e1_fetch(const float* __restrict__ xt, int m, int kg) {
  float4 z; z.x = z.y = z.z = z.w = 0.f;
  int t = m & 255;
  if (kg < 1024) {
    if (t == 0) return z;
    return *(const float4*)(xt + (((size_t)(m - 1)) << 10) + kg);
  } else if (kg < 2048) {
    return *(const float4*)(xt + (((size_t)m) << 10) + (kg - 1024));
  } else if (kg == 2048) {
    z.x = (float)t * (1.0f / 256.0f);
    return z;
  }
  return z;
}

// ---------------------------------------------------------------------------
// Tiled fp32 GEMM: C[M][N] = act(A[M][K] @ B[K][N] + bias). BM=128 BN=64 BK=16.
// SCATTER epilogue writes ctrl into comb prefix: comb[t][n>>2][b][n&3].
template <int AMODE, bool RELU, bool SCATTER>
__global__ __launch_bounds__(256, 2) void gemm_enc(
    const float* __restrict__ A, const float* __restrict__ Bw,
    const float* __restrict__ bias, float* __restrict__ C, int K, int N) {
  __shared__ float As[16][132];
  __shared__ float Bs[16][68];
  const int tid = threadIdx.x;
  const int m0 = blockIdx.x << 7;
  const int n0 = blockIdx.y << 6;
  const int rr = tid >> 4;
  const int cc = tid & 15;
  float acc[8][4];
#pragma unroll
  for (int i = 0; i < 8; i++)
#pragma unroll
    for (int j = 0; j < 4; j++) acc[i][j] = 0.f;

  const int ar = tid >> 2;
  const int akq = (tid & 3) << 2;
  const int bk = tid >> 4;
  const int bn = (tid & 15) << 2;

  for (int k0 = 0; k0 < K; k0 += 16) {
#pragma unroll
    for (int p = 0; p < 2; p++) {
      int m = m0 + ar + (p << 6);
      float4 v;
      if (AMODE == 1) v = e1_fetch(A, m, k0 + akq);
      else            v = *(const float4*)(A + (size_t)m * K + k0 + akq);
      As[akq + 0][ar + (p << 6)] = v.x;
      As[akq + 1][ar + (p << 6)] = v.y;
      As[akq + 2][ar + (p << 6)] = v.z;
      As[akq + 3][ar + (p << 6)] = v.w;
    }
    {
      float4 v; v.x = v.y = v.z = v.w = 0.f;
      if ((k0 + bk) < K && (n0 + bn) < N)
        v = *(const float4*)(Bw + (size_t)(k0 + bk) * N + n0 + bn);
      *(float4*)&Bs[bk][bn] = v;
    }
    __syncthreads();
#pragma unroll
    for (int kk = 0; kk < 16; kk++) {
      float a[8], b4[4];
      *(float4*)&a[0] = *(const float4*)&As[kk][rr << 3];
      *(float4*)&a[4] = *(const float4*)&As[kk][(rr << 3) + 4];
      *(float4*)&b4[0] = *(const float4*)&Bs[kk][cc << 2];
#pragma unroll
      for (int i = 0; i < 8; i++)
#pragma unroll
        for (int j = 0; j < 4; j++) acc[i][j] += a[i] * b4[j];
    }
    __syncthreads();
  }

  if (!SCATTER) {
#pragma unroll
    for (int i = 0; i < 8; i++) {
      int m = m0 + (rr << 3) + i;
      int n = n0 + (cc << 2);
      if (n + 3 < N) {
        float4 o;
        o.x = acc[i][0] + bias[n + 0];
        o.y = acc[i][1] + bias[n + 1];
        o.z = acc[i][2] + bias[n + 2];
        o.w = acc[i][3] + bias[n + 3];
        if (RELU) {
          o.x = fmaxf(o.x, 0.f); o.y = fmaxf(o.y, 0.f);
          o.z = fmaxf(o.z, 0.f); o.w = fmaxf(o.w, 0.f);
        }
        *(float4*)(C + (size_t)m * N + n) = o;
      } else {
#pragma unroll
        for (int j = 0; j < 4; j++) {
          if (n + j < N) {
            float v = acc[i][j] + bias[n + j];
            if (RELU) v = fmaxf(v, 0.f);
            C[(size_t)m * N + n + j] = v;
          }
        }
      }
    }
  } else {
    // ctrl -> comb prefix: m = b*256 + t; comb[t][n>>2][b][n&3]
#pragma unroll
    for (int i = 0; i < 8; i++) {
      int m = m0 + (rr << 3) + i;
      int t = m & 255, b = m >> 8;
#pragma unroll
      for (int j = 0; j < 4; j++) {
        int n = n0 + (cc << 2) + j;
        if (n < EN3)
          C[((size_t)t * 265 + (n >> 2)) * 256 + (b << 2) + (n & 3)] = acc[i][j] + bias[n];
      }
    }
  }
}

// ---------------------------------------------------------------------------
// GLOBAL zero-RMW flag barrier — verbatim r7 (proven in r7/r8). bar[w] is wg
// w's monotone generation flag. Arrive: one plain agent store. Detect: wave 0
// sweeps all 256 flags (one dwordx4 sc0sc1 per lane) + __all. Producer data
// is at MALL before the flag store (vmcnt drained at __syncthreads; all
// mutable stores agent-scope sc0sc1).
__device__ inline void gbar(unsigned* __restrict__ bar, unsigned gen, int w) {
  __syncthreads();
  if (threadIdx.x == 0)
    __hip_atomic_store(bar + w, gen, __ATOMIC_RELAXED, __HIP_MEMORY_SCOPE_AGENT);
  if (threadIdx.x < 64) {
    const unsigned* fp = bar + (threadIdx.x << 2);
    for (;;) {
      uint4v f;
      asm volatile(
          "global_load_dwordx4 %0, %1, off sc0 sc1\n\t"
          "s_waitcnt vmcnt(0)"
          : "=v"(f) : "v"(fp));
      if (__all(f.x >= gen && f.y >= gen && f.z >= gen && f.w >= gen)) break;
      __builtin_amdgcn_s_sleep(1);
    }
  }
  __syncthreads();
}

// ---------------------------------------------------------------------------
// One decoder layer phase for group g (8 rows), cols [base, base+NC).
// 1) Stage the group's act slice to LDS: NQ quads x 8 rows x 4 floats
//    (<=34 KB). Split issue/write: 5 float4 regs per thread, one latency
//    exposure. Plain cached loads — legal because the global barrier restores
//    the r7 protocol (line's first read strictly after its last write).
// 2) Compute: wave q does quads j ≡ q (mod 8) ascending (r7 k-order);
//    lane = [rloc:3][c8:3] -> row 8g+rloc, cols base+c8+8m (m<NCL).
// 3) LDS reduce q-ascending (r7 order) + bias + relu, agent dword store.
template <int NQ, int KPAD, bool RELU>
__device__ __forceinline__ void dec_phase(
    const float* __restrict__ actb, const float* __restrict__ wt,
    const float* __restrict__ bias, float* __restrict__ outb, int outk_off,
    int NC, int base, int g, int rloc, int c8, int q,
    float* __restrict__ lds_act, float* __restrict__ red, int tid) {
  // ---- stage (issue all, then write all: one latency exposure) ----
  constexpr int NE = NQ * 8;  // float4 count (2120/2096/2072)
  float4 sv[5];
#pragma unroll
  for (int s = 0; s < 5; s++) {
    int idx = tid + (s << 9);
    if (idx < NE)
      sv[s] = *(const float4*)(actb + ((size_t)(idx >> 3) << 8) +
                               (((g << 3) + (idx & 7)) << 2));
  }
#pragma unroll
  for (int s = 0; s < 5; s++) {
    int idx = tid + (s << 9);
    if (idx < NE)
      *(float4*)(lds_act + ((idx >> 3) << 5) + ((idx & 7) << 2)) = sv[s];
  }
  __syncthreads();

  // ---- compute ----
  float acc[5];
#pragma unroll
  for (int m = 0; m < 5; m++) acc[m] = 0.f;
  const int NCL = (NC - c8 + 7) >> 3;  // 4 or 5
  const float* wb = wt + (size_t)(base + c8) * KPAD;
#pragma unroll 2
  for (int j = q; j < NQ; j += 8) {
    float4 av = *(const float4*)(lds_act + (j << 5) + (rloc << 2));
    const float* wq = wb + (j << 2);
#pragma unroll
    for (int m = 0; m < 5; m++) {
      if (m < NCL) {
        float4 wv = *(const float4*)(wq + (size_t)(m << 3) * KPAD);
        acc[m] = fmaf(av.x, wv.x, acc[m]);
        acc[m] = fmaf(av.y, wv.y, acc[m]);
        acc[m] = fmaf(av.z, wv.z, acc[m]);
        acc[m] = fmaf(av.w, wv.w, acc[m]);
      }
    }
  }

  // ---- reduce (q ascending, r7 order) ----
  float* rp = red + tid * 9;
#pragma unroll
  for (int m = 0; m < 5; m++) rp[m] = acc[m];
  __syncthreads();
  const int nout = NC << 3;  // 8 rows x NC cols
  if (tid < nout) {
    int rr = tid / NC;
    int ci = tid - rr * NC;
    int cc8 = ci & 7, cm = ci >> 3;
    float s = 0.f;
#pragma unroll
    for (int q2 = 0; q2 < 8; q2++)
      s += red[((q2 << 6) + (rr << 3) + cc8) * 9 + cm];
    s += bias[base + ci];
    if (RELU) s = fmaxf(s, 0.f);
    int kk = outk_off + base + ci;
    int grow = (g << 3) + rr;
    __hip_atomic_store(outb + ((size_t)(kk >> 2) << 8) + (grow << 2) + (kk & 3), s,
                       __ATOMIC_RELAXED, __HIP_MEMORY_SCOPE_AGENT);
  }
}

// Persistent decoder: 256 wgs x 512 thr. Work partition: 8 row-groups x 32
// col-wgs (group g owns batch rows 8g..8g+7). Synchronization: GLOBAL flag
// barrier every phase (r7-proven; no group drift -> no stale-line hazard).
__global__ __launch_bounds__(512, 1) void decoder_kernel(
    const float* __restrict__ wt1, const float* __restrict__ b1,
    const float* __restrict__ wt2, const float* __restrict__ b2,
    const float* __restrict__ wt3, const float* __restrict__ b3,
    float* __restrict__ comb, float* __restrict__ h1s, float* __restrict__ h2s,
    unsigned* __restrict__ bar) {
  __shared__ float lds_act[265 * 32];  // 33,920 B
  __shared__ float red[512 * 9];       // 18,432 B
  const int tid = threadIdx.x;
  const int w = blockIdx.x;
  const int g = w >> 5;   // row-group 0..7
  const int il = w & 31;  // col-wg index within group
  const int lane = tid & 63;
  const int rloc = lane >> 3;
  const int c8 = lane & 7;
  const int q = __builtin_amdgcn_readfirstlane(tid >> 6);

  // col partitions over 32 wgs
  // L1: 22 x 33 + 10 x 32 = 1046
  const int nc1 = (il < 22) ? 33 : 32;
  const int cb1 = (il < 22) ? il * 33 : 726 + (il - 22) * 32;
  // L2: 11 x 33 + 21 x 32 = 1035
  const int nc2 = (il < 11) ? 33 : 32;
  const int cb2 = (il < 11) ? il * 33 : 363 + (il - 11) * 32;
  // L3: 32 x 32 = 1024
  const int cb3 = il << 5;

  unsigned gen = 0;
  for (int t = 0; t < TT; t++) {
    gen++; gbar(bar, gen, w);
    dec_phase<NQ1, KP1, true>(comb + (size_t)t * COMB_SLOT, wt1, b1,
                              h1s + (size_t)t * H1_SLOT, 0,
                              nc1, cb1, g, rloc, c8, q, lds_act, red, tid);
    gen++; gbar(bar, gen, w);
    dec_phase<NQ2, KP2, true>(h1s + (size_t)t * H1_SLOT, wt2, b2,
                              h2s + (size_t)t * H2_SLOT, 0,
                              nc2, cb2, g, rloc, c8, q, lds_act, red, tid);
    gen++; gbar(bar, gen, w);
    dec_phase<NQ3, KP3, false>(h2s + (size_t)t * H2_SLOT, wt3, b3,
                               comb + (size_t)(t + 1) * COMB_SLOT, 32,
                               32, cb3, g, rloc, c8, q, lds_act, red, tid);
  }
}

// ---------------------------------------------------------------------------
// comb[t+1][8+Q][b][kk] -> out[b][4Q+kk][t]. grid (256 quads, 4 t-tiles), 256 thr.
__global__ void permute_out2(const float* __restrict__ comb, float* __restrict__ out) {
  __shared__ float tl[64 * 261];  // [r] stride 261, [kk] stride 65, [tt]
  int Q = blockIdx.x;
  int t0 = blockIdx.y << 6;
  int tid = threadIdx.x;
  int r = tid & 63, ts = tid >> 6;  // ts 0..3
#pragma unroll
  for (int i = 0; i < 16; i++) {
    int tt = (i << 2) + ts;
    float4 v = *(const float4*)(comb + ((size_t)(t0 + tt + 1) * 265 + 8 + Q) * 256 + (r << 2));
    float* p = &tl[r * 261];
    p[tt] = v.x; p[65 + tt] = v.y; p[130 + tt] = v.z; p[195 + tt] = v.w;
  }
  __syncthreads();
  int kk = tid & 3, r2 = tid >> 2;
  const float* p = &tl[r2 * 261 + kk * 65];
  float* o = out + ((size_t)r2 * 1024 + (Q << 2) + kk) * 256 + t0;
#pragma unroll
  for (int i = 0; i < 16; i++) {
    int b = i << 2;
    float4 v;
    v.x = p[b]; v.y = p[b + 1]; v.z = p[b + 2]; v.w = p[b + 3];
    *(float4*)(o + b) = v;
  }
}

// ---------------------------------------------------------------------------
extern "C" void kernel_launch(void* const* d_in, const int* in_sizes, int n_in,
                              void* d_out, int out_size, void* d_ws, size_t ws_size,
                              hipStream_t stream) {
  (void)in_sizes; (void)n_in; (void)out_size; (void)ws_size;
  const float* x   = (const float*)d_in[0];
  const float* eW1 = (const float*)d_in[1];
  const float* eb1 = (const float*)d_in[2];
  const float* eW2 = (const float*)d_in[3];
  const float* eb2 = (const float*)d_in[4];
  const float* eW3 = (const float*)d_in[5];
  const float* eb3 = (const float*)d_in[6];
  const float* dW1 = (const float*)d_in[7];
  const float* db1 = (const float*)d_in[8];
  const float* dW2 = (const float*)d_in[9];
  const float* db2 = (const float*)d_in[10];
  const float* dW3 = (const float*)d_in[11];
  const float* db3 = (const float*)d_in[12];

  float* ws    = (float*)d_ws;
  float* xt    = ws + OFF_XT;
  float* wt1p  = ws + OFF_WT1;
  float* wt2p  = ws + OFF_WT2;
  float* wt3p  = ws + OFF_WT3;
  float* h1sp  = ws + OFF_H1S;
  float* h2sp  = ws + OFF_H2S;
  float* e1p   = ws + OFF_E1;
  float* e2p   = ws + OFF_E2;
  float* combp = ws + OFF_COMB;
  unsigned* barp = (unsigned*)(ws + OFF_BAR);

  // zero comb slot 0 (t=0 "previous stft" = 0) and barrier flags
  zero_init<<<dim3(64), dim3(256), 0, stream>>>(combp, (size_t)COMB_SLOT);
  zero_init<<<dim3(1), dim3(256), 0, stream>>>((float*)barp, (size_t)2048);

  transpose_x<<<dim3(32, 8, 64), dim3(256), 0, stream>>>(x, xt);

  // encoder (E1 consumes xt; xt/E1/E2 regions are reused for WT/h-slots after)
  gemm_enc<1, true,  false><<<dim3(128, 15), dim3(256), 0, stream>>>(xt,  eW1, eb1, e1p, EK1, EN1);
  gemm_enc<0, true,  false><<<dim3(128, 7),  dim3(256), 0, stream>>>(e1p, eW2, eb2, e2p, EN1, EN2);
  gemm_enc<0, false, true ><<<dim3(128, 1),  dim3(256), 0, stream>>>(e2p, eW3, eb3, combp, EN2, EN3);

  // decoder weight transposes (after E1 so xt region is dead)
  transpose_w<<<dim3(33, 34), dim3(256), 0, stream>>>(dW1, wt1p, 1057, DN1, KP1, WROWS1);
  transpose_w<<<dim3(33, 33), dim3(256), 0, stream>>>(dW2, wt2p, 1046, DN2, KP2, WROWS2);
  transpose_w<<<dim3(33, 33), dim3(256), 0, stream>>>(dW3, wt3p, 1035, DN3, KP3, WROWS3);
  init_tail<<<dim3(64), dim3(256), 0, stream>>>(combp);

  // persistent cooperative decoder
  const float *a0 = wt1p, *a1 = db1, *a2 = wt2p, *a3 = db2, *a4 = wt3p, *a5 = db3;
  float *r0 = combp, *r1 = h1sp, *r2 = h2sp;
  unsigned* r3 = barp;
  void* kargs[] = {&a0, &a1, &a2, &a3, &a4, &a5, &r0, &r1, &r2, &r3};
  hipLaunchCooperativeKernel((void*)decoder_kernel, dim3(256), dim3(512), kargs,
                             0, stream);

  permute_out2<<<dim3(256, 4), dim3(256), 0, stream>>>(combp, (float*)d_out);
}